// Round 11
// baseline (1021.676 us; speedup 1.0000x reference)
//
#include <hip/hip_runtime.h>
#include <hip/hip_bf16.h>

#define DD   64      // feature dim
#define NL   5       // layers
#define NT   37      // classes
#define LD   (NL*DD) // 320
#define PB   16      // CSR row padding quantum = gather clause depth

typedef __attribute__((ext_vector_type(8))) short short8;   // 8 bf16 = 4 VGPRs
typedef __attribute__((ext_vector_type(4))) float f32x4;    // MFMA accumulator
typedef __attribute__((ext_vector_type(4))) int   i32x4;

static __device__ __forceinline__ int padq(int d) { return (d + PB - 1) & ~(PB - 1); }
static __device__ __forceinline__ short bf16_bits(float f) {
    __hip_bfloat16 h = __float2bfloat16(f);
    return __builtin_bit_cast(short, h);
}
static __device__ __forceinline__ float bf2f(short s) {
    return __int_as_float(((int)(unsigned short)s) << 16);
}

// ---------------------------------------------------------------------------
// Merged init: x -> bf16 h table, and W_mlp -> transposed bf16 Wt
__global__ void init_kernel(const float* __restrict__ x, __hip_bfloat16* __restrict__ hb,
                            size_t n1, const float* __restrict__ W,
                            __hip_bfloat16* __restrict__ Wt, int n2) {
    size_t i = (size_t)blockIdx.x * blockDim.x + threadIdx.x;
    if (i < n1) {
        hb[i] = __float2bfloat16(x[i]);
    } else {
        size_t id = i - n1;
        if (id < (size_t)n2) {
            int l = (int)(id / (DD * DD));
            int r = (int)(id % (DD * DD));
            int c = r / DD, k = r % DD;
            Wt[(size_t)l * DD * DD + c * DD + k] =
                __float2bfloat16(W[(size_t)l * DD * DD + k * DD + c]);
        }
    }
}

// ---------------------------------------------------------------------------
// CSR build: degree histogram
__global__ void deg_kernel(const int* __restrict__ dst, int* __restrict__ deg, int E) {
    int e = blockIdx.x * blockDim.x + threadIdx.x;
    if (e < E) atomicAdd(&deg[dst[e]], 1);
}

// scans operate on PADDED degrees (rows padded to multiple of PB)
__global__ void chunksum_kernel(const int* __restrict__ deg, int* __restrict__ csum, int n) {
    __shared__ int sm[256];
    int tid = threadIdx.x;
    int base = blockIdx.x * 1024 + tid * 4;
    int s = 0;
#pragma unroll
    for (int j = 0; j < 4; ++j) s += (base + j < n) ? padq(deg[base + j]) : 0;
    sm[tid] = s;
    __syncthreads();
    for (int off = 128; off > 0; off >>= 1) {
        if (tid < off) sm[tid] += sm[tid + off];
        __syncthreads();
    }
    if (tid == 0) csum[blockIdx.x] = sm[0];
}

__global__ void scansums_kernel(int* __restrict__ csum, int nc, int* __restrict__ tot) {
    __shared__ int sm[256];
    int tid = threadIdx.x;
    int base = tid * 4;
    int v[4]; int s = 0;
#pragma unroll
    for (int j = 0; j < 4; ++j) { v[j] = (base + j < nc) ? csum[base + j] : 0; s += v[j]; }
    sm[tid] = s;
    __syncthreads();
    for (int off = 1; off < 256; off <<= 1) {
        int t = (tid >= off) ? sm[tid - off] : 0;
        __syncthreads();
        sm[tid] += t;
        __syncthreads();
    }
    int p = sm[tid] - s;
#pragma unroll
    for (int j = 0; j < 4; ++j) { if (base + j < nc) csum[base + j] = p; p += v[j]; }
    if (tid == 255) *tot = p;
}

__global__ void chunkscan_kernel(const int* __restrict__ deg, const int* __restrict__ csum,
                                 int* __restrict__ rowptr, int* __restrict__ cursor, int n) {
    __shared__ int sm[256];
    int tid = threadIdx.x;
    int base = blockIdx.x * 1024 + tid * 4;
    int v[4]; int s = 0;
#pragma unroll
    for (int j = 0; j < 4; ++j) { v[j] = (base + j < n) ? padq(deg[base + j]) : 0; s += v[j]; }
    sm[tid] = s;
    __syncthreads();
    for (int off = 1; off < 256; off <<= 1) {
        int t = (tid >= off) ? sm[tid - off] : 0;
        __syncthreads();
        sm[tid] += t;
        __syncthreads();
    }
    int p = sm[tid] - s + csum[blockIdx.x];
#pragma unroll
    for (int j = 0; j < 4; ++j) {
        if (base + j < n) { rowptr[base + j] = p; cursor[base + j] = p; }
        p += v[j];
    }
}

// Phase A: scatter ONLY the 4-B permutation (plain stores -> L2 can merge).
__global__ void fill_kernel(const int* __restrict__ dst, int* __restrict__ cursor,
                            int* __restrict__ col, int E) {
    int e = blockIdx.x * blockDim.x + threadIdx.x;
    if (e >= E) return;
    int p = atomicAdd(&cursor[dst[e]], 1);
    col[p] = e;
}

// Pad slots: col = -1 marks a pad.
__global__ void padfill_kernel(const int* __restrict__ deg, const int* __restrict__ rowptr,
                               int* __restrict__ col, int n) {
    int v = blockIdx.x * blockDim.x + threadIdx.x;
    if (v >= n) return;
    int s = rowptr[v] + deg[v];
    int e = rowptr[v + 1];
    for (int i = s; i < e; ++i) col[i] = -1;
}

// Phase B: slot-ordered streaming pack. Sequential NT writes.
// Record slot 7 = flag (1.0 real / 0.0 pad); pads gather row 0 (hot line).
template<bool PACKED>
__global__ void pack_kernel(const int* __restrict__ col, const int* __restrict__ src,
                            const float* __restrict__ ea,
                            int* __restrict__ srcv, short* __restrict__ eab,
                            const int* __restrict__ totp) {
    int p = blockIdx.x * blockDim.x + threadIdx.x;
    if (p >= *totp) return;
    int e = col[p];
    bool real = (e >= 0);
    int ec = real ? e : 0;
    __builtin_nontemporal_store(real ? src[ec] : 0, &srcv[p]);
    if (PACKED) {
        const float* a = ea + (size_t)ec * 7;
        short8 r;
#pragma unroll
        for (int k = 0; k < 7; ++k) r[k] = bf16_bits(a[k]);
        r[7] = real ? (short)0x3F80 : (short)0;   // bf16 1.0 / 0.0
        i32x4 ri = __builtin_bit_cast(i32x4, r);
        __builtin_nontemporal_store(ri, (i32x4*)(eab + (size_t)p * 8));
    }
}

// ---------------------------------------------------------------------------
// Aggregation: one WAVE per node, lane = feature. BRANCH-FREE batch body:
// full padded row processed; pads contribute exactly 0 via the record flag.
// Single basic block => compiler can clause all PB gathers.
template<bool PACKED>
__global__ __launch_bounds__(256, 4)
void agg_kernel(const __hip_bfloat16* __restrict__ hb_in,
                const short* __restrict__ eab,
                const int* __restrict__ col, const int* __restrict__ srcv,
                const float* __restrict__ ea,
                const int* __restrict__ rowptr,
                const float* __restrict__ W_edge, const float* __restrict__ b_edge,
                const float* __restrict__ eps, int layer,
                __hip_bfloat16* __restrict__ u, int n) {
    int lane = threadIdx.x & 63;
    int v = __builtin_amdgcn_readfirstlane(blockIdx.x * 4 + (threadIdx.x >> 6));
    if (v >= n) return;   // wave-uniform

    float we[7];
#pragma unroll
    for (int k = 0; k < 7; ++k) we[k] = W_edge[k * DD + lane];
    float be = b_edge[lane];
    float epsv = 1.f + eps[layer];

    float acc = 0.f;
    int beg = rowptr[v];
    int end = rowptr[v + 1];     // padded end; multiple of PB slots
    for (int p = beg; p < end; p += PB) {
        // --- unconditional index loads (wave-uniform -> SGPR)
        int S[PB];
#pragma unroll
        for (int j = 0; j < PB; ++j) S[j] = srcv[p + j];
        // --- unconditional gather clause: PB loads, shared voffset, SGPR bases
        __hip_bfloat16 hv[PB];
#pragma unroll
        for (int j = 0; j < PB; ++j) hv[j] = hb_in[(size_t)S[j] * DD + lane];
        // --- unconditional edge-record loads (wave-uniform -> scalarized)
        float ev[PB][7];
        float fl[PB];
        if (PACKED) {
            short8 eb[PB];
#pragma unroll
            for (int j = 0; j < PB; ++j)
                eb[j] = *((const short8*)(eab + (size_t)(p + j) * 8));
#pragma unroll
            for (int j = 0; j < PB; ++j) {
#pragma unroll
                for (int k = 0; k < 7; ++k) ev[j][k] = bf2f(eb[j][k]);
                fl[j] = bf2f(eb[j][7]);
            }
        } else {
            int EJ[PB];
#pragma unroll
            for (int j = 0; j < PB; ++j) {
                int e = col[p + j];
                fl[j] = (e >= 0) ? 1.f : 0.f;
                EJ[j] = (e >= 0) ? e : 0;
            }
#pragma unroll
            for (int j = 0; j < PB; ++j) {
                const float* a = ea + (size_t)EJ[j] * 7;
#pragma unroll
                for (int k = 0; k < 7; ++k) ev[j][k] = a[k];
            }
        }
        // --- branch-free VALU: pads multiply to exact 0
#pragma unroll
        for (int j = 0; j < PB; ++j) {
            float emb = be + ev[j][0] * we[0] + ev[j][1] * we[1] + ev[j][2] * we[2]
                           + ev[j][3] * we[3] + ev[j][4] * we[4] + ev[j][5] * we[5]
                           + ev[j][6] * we[6];
            float tv = __bfloat162float(hv[j]) + emb;
            acc += fmaxf(tv, 0.f) * fl[j];
        }
    }
    float self = __bfloat162float(hb_in[(size_t)v * DD + lane]);
    u[(size_t)v * DD + lane] = __float2bfloat16(epsv * self + acc);
}

// ---------------------------------------------------------------------------
// MFMA MLP: h_out = relu(u @ W + b). Wave handles 16 nodes; A from global u,
// B from pre-transposed bf16 Wt[c][k]. Fragment mapping validated in R5.
__global__ __launch_bounds__(256, 4)
void mlp_mfma_kernel(const __hip_bfloat16* __restrict__ u,
                     const __hip_bfloat16* __restrict__ Wt,
                     const float* __restrict__ bmlp,
                     __hip_bfloat16* __restrict__ hb_out, int n) {
    int lane = threadIdx.x & 63;
    int wid  = threadIdx.x >> 6;
    int colx = lane & 15;
    int quad = lane >> 4;
    int v0 = __builtin_amdgcn_readfirstlane((blockIdx.x * 4 + wid) * 16);
    if (v0 >= n) return;

    short8 wf[4][2];
#pragma unroll
    for (int t = 0; t < 4; ++t)
#pragma unroll
        for (int s = 0; s < 2; ++s)
            wf[t][s] = *((const short8*)(Wt + (size_t)(t * 16 + colx) * DD + s * 32 + quad * 8));
    float bias[4];
#pragma unroll
    for (int t = 0; t < 4; ++t) bias[t] = bmlp[t * 16 + colx];

    int vr = v0 + colx;
    int vrc = (vr < n) ? vr : (n - 1);
    const __hip_bfloat16* up = u + (size_t)vrc * DD;
    short8 a0 = *((const short8*)(up + quad * 8));
    short8 a1 = *((const short8*)(up + 32 + quad * 8));

    f32x4 acc[4] = {{0.f, 0.f, 0.f, 0.f}, {0.f, 0.f, 0.f, 0.f},
                    {0.f, 0.f, 0.f, 0.f}, {0.f, 0.f, 0.f, 0.f}};
#pragma unroll
    for (int t = 0; t < 4; ++t) {
        acc[t] = __builtin_amdgcn_mfma_f32_16x16x32_bf16(a0, wf[t][0], acc[t], 0, 0, 0);
        acc[t] = __builtin_amdgcn_mfma_f32_16x16x32_bf16(a1, wf[t][1], acc[t], 0, 0, 0);
    }

#pragma unroll
    for (int r = 0; r < 4; ++r) {
        int v = v0 + quad * 4 + r;
        if (v < n) {
#pragma unroll
            for (int t = 0; t < 4; ++t) {
                float val = acc[t][r] + bias[t];
                val = (val > 0.f) ? val : 0.f;
                hb_out[(size_t)v * DD + t * 16 + colx] = __float2bfloat16(val);
            }
        }
    }
}

// ---------------------------------------------------------------------------
// Pool partials: one block per (graph, layer). Zero atomics.
__global__ void pool_part_kernel(const __hip_bfloat16* __restrict__ htabs, size_t lstride,
                                 const int* __restrict__ batch,
                                 float* __restrict__ g_sum, int n, int G) {
    __shared__ float part[4][DD];
    __shared__ int bnd[2];
    int g = blockIdx.x / NL;
    int q = blockIdx.x % NL;
    int tid = threadIdx.x;
    if (tid < 2) {
        int target = g + tid;
        int lo = 0, hi = n;
        while (lo < hi) { int mid = (lo + hi) >> 1; if (batch[mid] < target) lo = mid + 1; else hi = mid; }
        bnd[tid] = lo;
    }
    __syncthreads();
    int lb = bnd[0], ub = bnd[1];
    int w = tid >> 6, f = tid & 63;
    const __hip_bfloat16* T = htabs + (size_t)q * lstride;
    float s = 0.f;
    for (int v = lb + w; v < ub; v += 4)
        s += __bfloat162float(T[(size_t)v * DD + f]);
    part[w][f] = s;
    __syncthreads();
    if (tid < DD) {
        float tot = part[0][f] + part[1][f] + part[2][f] + part[3][f];
        float c = (float)(ub - lb);
        if (c < 1.f) c = 1.f;
        g_sum[(size_t)g * LD + q * DD + f] = tot / c;
    }
}

__global__ void readout_mean_kernel(const float* __restrict__ g_mean,
                                    const float* __restrict__ W_pred,
                                    const float* __restrict__ b_pred,
                                    float* __restrict__ out, int G) {
    int id = blockIdx.x * blockDim.x + threadIdx.x;
    if (id >= G * NT) return;
    int g = id / NT, t = id % NT;
    float acc = b_pred[t];
    const float* gs = g_mean + (size_t)g * LD;
    for (int k = 0; k < LD; ++k) acc += gs[k] * W_pred[k * NT + t];
    out[id] = acc;
}

// ---------------------------------------------------------------------------
// Tier-2 fallback pool (run accumulation) + readout
__global__ void pool_kernel(const __hip_bfloat16* __restrict__ h, const int* __restrict__ batch,
                            float* __restrict__ g_sum, int layer, int n) {
    int wave = (blockIdx.x * blockDim.x + threadIdx.x) >> 6;
    int l = threadIdx.x & 63;
    int v0 = wave * 64;
    if (v0 >= n) return;
    int vend = min(v0 + 64, n);
    int cur = batch[v0];
    float acc = 0.f;
    for (int v = v0; v < vend; ++v) {
        int bv = batch[v];
        if (bv != cur) {
            atomicAdd(&g_sum[(size_t)cur * LD + layer * DD + l], acc);
            acc = 0.f;
            cur = bv;
        }
        acc += __bfloat162float(h[(size_t)v * DD + l]);
    }
    atomicAdd(&g_sum[(size_t)cur * LD + layer * DD + l], acc);
}

__global__ void graph_cnt_kernel(const int* __restrict__ batch, int* __restrict__ cnt,
                                 int n, int G) {
    int g = blockIdx.x * blockDim.x + threadIdx.x;
    if (g >= G) return;
    int lo = 0, hi = n;
    while (lo < hi) { int mid = (lo + hi) >> 1; if (batch[mid] < g) lo = mid + 1; else hi = mid; }
    int lb0 = lo;
    lo = lb0; hi = n;
    while (lo < hi) { int mid = (lo + hi) >> 1; if (batch[mid] < g + 1) lo = mid + 1; else hi = mid; }
    cnt[g] = lo - lb0;
}

__global__ void readout_kernel(const float* __restrict__ g_sum, const int* __restrict__ cnt,
                               const float* __restrict__ W_pred, const float* __restrict__ b_pred,
                               float* __restrict__ out, int G) {
    int id = blockIdx.x * blockDim.x + threadIdx.x;
    if (id >= G * NT) return;
    int g = id / NT, t = id % NT;
    float c = (float)cnt[g];
    if (c < 1.f) c = 1.f;
    float inv = 1.f / c;
    float acc = b_pred[t];
    const float* gs = g_sum + (size_t)g * LD;
    for (int k = 0; k < LD; ++k) acc += gs[k] * inv * W_pred[k * NT + t];
    out[id] = acc;
}

// ---------------------------------------------------------------------------
extern "C" void kernel_launch(void* const* d_in, const int* in_sizes, int n_in,
                              void* d_out, int out_size, void* d_ws, size_t ws_size,
                              hipStream_t stream) {
    const float* x       = (const float*)d_in[0];
    const int*   eidx    = (const int*)d_in[1];
    const float* ea      = (const float*)d_in[2];
    const int*   batch   = (const int*)d_in[3];
    const float* W_edge  = (const float*)d_in[4];
    const float* b_edge  = (const float*)d_in[5];
    const float* eps     = (const float*)d_in[6];
    const float* W_mlp   = (const float*)d_in[7];
    const float* b_mlp   = (const float*)d_in[8];
    const float* W_pred  = (const float*)d_in[9];
    const float* b_pred  = (const float*)d_in[10];
    float* out = (float*)d_out;

    const int N = in_sizes[3];          // 100000
    const int E = in_sizes[2] / 7;      // 1250000
    const int G = out_size / NT;        // 128
    const int* src = eidx;              // edge_index[0]
    const int* dst = eidx + E;          // edge_index[1]
    const int NC = (N + 1023) / 1024;
    const size_t SLOTS = (size_t)E + (size_t)(PB - 1) * N;   // padded-slot capacity

    const size_t S_h = (size_t)N * DD * 2;   // one bf16 table
    const size_t small = (size_t)N * 4 + (size_t)(N + 4) * 4 + (size_t)N * 4 + 4096
                       + (size_t)NL * DD * DD * 2              // Wt
                       + (size_t)G * LD * 4 + (((size_t)G * 4 + 15) & ~(size_t)15);
    const size_t needA = 7 * S_h + small + SLOTS * 24;  // eab + col + srcv
    const size_t needB = 7 * S_h + small + SLOTS * 8;   // col + srcv
    const int tier = (ws_size >= needA) ? 0 : (ws_size >= needB) ? 1 : 2;
    const int nTab = (tier <= 1) ? 6 : 2;

    char* w = (char*)d_ws;
    __hip_bfloat16* hbt = (__hip_bfloat16*)w;  w += (size_t)nTab * S_h;
    __hip_bfloat16* u   = (__hip_bfloat16*)w;  w += S_h;
    __hip_bfloat16* Wt  = (__hip_bfloat16*)w;  w += (size_t)NL * DD * DD * 2;
    int*   deg    = (int*)w;                   w += (size_t)N * 4;
    int*   rowptr = (int*)w;                   w += (size_t)(N + 4) * 4;
    int*   cursor = (int*)w;                   w += (size_t)N * 4;
    int*   csum   = (int*)w;                   w += 4096;
    float* g_sum  = (float*)w;                 w += (size_t)G * LD * 4;
    int*   cnt    = (int*)w;                   w += ((size_t)G * 4 + 15) & ~(size_t)15;
    short* eab = nullptr; int* col = nullptr; int* srcv = nullptr;
    if (tier == 0) {
        eab  = (short*)w;  w += SLOTS * 16;    // 16-B aligned
        col  = (int*)w;    w += SLOTS * 4;
        srcv = (int*)w;
    } else {
        col  = (int*)w;    w += SLOTS * 4;
        srcv = (int*)w;
    }
    const bool packed = (tier == 0);

    hipMemsetAsync(deg, 0, (size_t)N * 4, stream);
    if (tier == 2) hipMemsetAsync(g_sum, 0, (size_t)G * LD * 4, stream);

    {
        size_t n1 = (size_t)N * DD;
        size_t tot = n1 + (size_t)NL * DD * DD;
        init_kernel<<<(unsigned)((tot + 255) / 256), 256, 0, stream>>>(
            x, hbt, n1, W_mlp, Wt, NL * DD * DD);
    }

    // CSR build (padded rows): histogram -> scan -> scatter col -> pad -> pack
    deg_kernel<<<(E + 255) / 256, 256, 0, stream>>>(dst, deg, E);
    chunksum_kernel<<<NC, 256, 0, stream>>>(deg, csum, N);
    scansums_kernel<<<1, 256, 0, stream>>>(csum, NC, rowptr + N);
    chunkscan_kernel<<<NC, 256, 0, stream>>>(deg, csum, rowptr, cursor, N);
    fill_kernel<<<(E + 255) / 256, 256, 0, stream>>>(dst, cursor, col, E);
    padfill_kernel<<<(N + 255) / 256, 256, 0, stream>>>(deg, rowptr, col, N);
    {
        unsigned pblocks = (unsigned)((SLOTS + 255) / 256);
        if (packed)
            pack_kernel<true><<<pblocks, 256, 0, stream>>>(col, src, ea, srcv, eab,
                                                           rowptr + N);
        else
            pack_kernel<false><<<pblocks, 256, 0, stream>>>(col, src, ea, srcv, eab,
                                                            rowptr + N);
    }

    int aggBlocks = (N + 3) / 4;
    int mlpBlocks = (N + 63) / 64;
    for (int i = 0; i < NL; ++i) {
        __hip_bfloat16* hin  = (tier <= 1) ? (hbt + (size_t)i * N * DD)
                                           : (hbt + (size_t)(i & 1) * N * DD);
        __hip_bfloat16* hout = (tier <= 1) ? (hbt + (size_t)(i + 1) * N * DD)
                                           : (hbt + (size_t)((i + 1) & 1) * N * DD);
        if (packed)
            agg_kernel<true><<<aggBlocks, 256, 0, stream>>>(
                hin, eab, col, srcv, ea, rowptr, W_edge, b_edge, eps, i, u, N);
        else
            agg_kernel<false><<<aggBlocks, 256, 0, stream>>>(
                hin, eab, col, srcv, ea, rowptr, W_edge, b_edge, eps, i, u, N);
        mlp_mfma_kernel<<<mlpBlocks, 256, 0, stream>>>(
            u, Wt + (size_t)i * DD * DD, b_mlp + (size_t)i * DD, hout, N);
        if (tier == 2)
            pool_kernel<<<((N + 63) / 64 * 64 + 255) / 256, 256, 0, stream>>>(hout, batch,
                                                                              g_sum, i, N);
    }

    if (tier <= 1) {
        pool_part_kernel<<<G * NL, 256, 0, stream>>>(hbt + (size_t)N * DD, (size_t)N * DD,
                                                     batch, g_sum, N, G);
        readout_mean_kernel<<<(G * NT + 255) / 256, 256, 0, stream>>>(g_sum, W_pred, b_pred,
                                                                      out, G);
    } else {
        graph_cnt_kernel<<<1, 128, 0, stream>>>(batch, cnt, N, G);
        readout_kernel<<<(G * NT + 255) / 256, 256, 0, stream>>>(g_sum, cnt, W_pred, b_pred,
                                                                 out, G);
    }
}

// Round 12
// 863.711 us; speedup vs baseline: 1.1829x; 1.1829x over previous
//
#include <hip/hip_runtime.h>
#include <hip/hip_bf16.h>

#define DD   64      // feature dim
#define NL   5       // layers
#define NT   37      // classes
#define LD   (NL*DD) // 320
#define PB   16      // CSR row padding quantum = gather batch depth

typedef __attribute__((ext_vector_type(8))) short short8;   // 8 bf16 = 4 VGPRs
typedef __attribute__((ext_vector_type(4))) float f32x4;    // MFMA accumulator
typedef __attribute__((ext_vector_type(4))) int   i32x4;

static __device__ __forceinline__ int padq(int d) { return (d + PB - 1) & ~(PB - 1); }
static __device__ __forceinline__ short bf16_bits(float f) {
    __hip_bfloat16 h = __float2bfloat16(f);
    return __builtin_bit_cast(short, h);
}
static __device__ __forceinline__ float bf2f(short s) {
    return __int_as_float(((int)(unsigned short)s) << 16);
}

// ---------------------------------------------------------------------------
// Fused init: x -> bf16 h table, W_mlp -> transposed bf16 Wt, AND deg histogram.
__global__ void init_kernel(const float* __restrict__ x, __hip_bfloat16* __restrict__ hb,
                            size_t n1, const float* __restrict__ W,
                            __hip_bfloat16* __restrict__ Wt, int n2,
                            const int* __restrict__ dst, int* __restrict__ deg, int E) {
    size_t i = (size_t)blockIdx.x * blockDim.x + threadIdx.x;
    if (i < n1) {
        hb[i] = __float2bfloat16(x[i]);
    } else if (i < n1 + (size_t)n2) {
        size_t id = i - n1;
        int l = (int)(id / (DD * DD));
        int r = (int)(id % (DD * DD));
        int c = r / DD, k = r % DD;
        Wt[(size_t)l * DD * DD + c * DD + k] =
            __float2bfloat16(W[(size_t)l * DD * DD + k * DD + c]);
    } else {
        size_t e = i - n1 - (size_t)n2;
        if (e < (size_t)E) atomicAdd(&deg[dst[e]], 1);
    }
}

// ---------------------------------------------------------------------------
// scans operate on PADDED degrees (rows padded to multiple of PB)
__global__ void chunksum_kernel(const int* __restrict__ deg, int* __restrict__ csum, int n) {
    __shared__ int sm[256];
    int tid = threadIdx.x;
    int base = blockIdx.x * 1024 + tid * 4;
    int s = 0;
#pragma unroll
    for (int j = 0; j < 4; ++j) s += (base + j < n) ? padq(deg[base + j]) : 0;
    sm[tid] = s;
    __syncthreads();
    for (int off = 128; off > 0; off >>= 1) {
        if (tid < off) sm[tid] += sm[tid + off];
        __syncthreads();
    }
    if (tid == 0) csum[blockIdx.x] = sm[0];
}

__global__ void scansums_kernel(int* __restrict__ csum, int nc, int* __restrict__ tot) {
    __shared__ int sm[256];
    int tid = threadIdx.x;
    int base = tid * 4;
    int v[4]; int s = 0;
#pragma unroll
    for (int j = 0; j < 4; ++j) { v[j] = (base + j < nc) ? csum[base + j] : 0; s += v[j]; }
    sm[tid] = s;
    __syncthreads();
    for (int off = 1; off < 256; off <<= 1) {
        int t = (tid >= off) ? sm[tid - off] : 0;
        __syncthreads();
        sm[tid] += t;
        __syncthreads();
    }
    int p = sm[tid] - s;
#pragma unroll
    for (int j = 0; j < 4; ++j) { if (base + j < nc) csum[base + j] = p; p += v[j]; }
    if (tid == 255) *tot = p;
}

__global__ void chunkscan_kernel(const int* __restrict__ deg, const int* __restrict__ csum,
                                 int* __restrict__ rowptr, int* __restrict__ cursor, int n) {
    __shared__ int sm[256];
    int tid = threadIdx.x;
    int base = blockIdx.x * 1024 + tid * 4;
    int v[4]; int s = 0;
#pragma unroll
    for (int j = 0; j < 4; ++j) { v[j] = (base + j < n) ? padq(deg[base + j]) : 0; s += v[j]; }
    sm[tid] = s;
    __syncthreads();
    for (int off = 1; off < 256; off <<= 1) {
        int t = (tid >= off) ? sm[tid - off] : 0;
        __syncthreads();
        sm[tid] += t;
        __syncthreads();
    }
    int p = sm[tid] - s + csum[blockIdx.x];
#pragma unroll
    for (int j = 0; j < 4; ++j) {
        if (base + j < n) { rowptr[base + j] = p; cursor[base + j] = p; }
        p += v[j];
    }
}

// Single-pass fill (R9 winner): scatter 16-B bf16 record + 4-B srcv with NT stores.
template<bool PACKED>
__global__ void fill_kernel(const int* __restrict__ dst, const int* __restrict__ src,
                            const float* __restrict__ ea, int* __restrict__ cursor,
                            short* __restrict__ eab, int* __restrict__ col,
                            int* __restrict__ srcv, int E) {
    int e = blockIdx.x * blockDim.x + threadIdx.x;
    if (e >= E) return;
    int p = atomicAdd(&cursor[dst[e]], 1);
    int s = src[e];
    __builtin_nontemporal_store(s, &srcv[p]);
    if (PACKED) {
        const float* a = ea + (size_t)e * 7;
        short8 r;
#pragma unroll
        for (int k = 0; k < 7; ++k) r[k] = bf16_bits(a[k]);
        r[7] = 0;
        i32x4 ri = __builtin_bit_cast(i32x4, r);
        __builtin_nontemporal_store(ri, (i32x4*)(eab + (size_t)p * 8));
    } else {
        __builtin_nontemporal_store(e, &col[p]);
    }
}

// Pad slots: srcv=0 (safe in-bounds dummy gather); pad records never enter VALU.
__global__ void padfill_kernel(const int* __restrict__ deg, const int* __restrict__ rowptr,
                               int* __restrict__ srcv, int* __restrict__ col,
                               int has_col, int n) {
    int v = blockIdx.x * blockDim.x + threadIdx.x;
    if (v >= n) return;
    int s = rowptr[v] + deg[v];
    int e = rowptr[v + 1];
    for (int i = s; i < e; ++i) {
        srcv[i] = 0;
        if (has_col) col[i] = 0;
    }
}

// ---------------------------------------------------------------------------
// Aggregation (R10 winner): one WAVE per node, lane = feature. Rows padded to
// PB=16: all loads unconditional; VALU guarded by true degree.
template<bool PACKED>
__global__ __launch_bounds__(256, 4)
void agg_kernel(const __hip_bfloat16* __restrict__ hb_in,
                const short* __restrict__ eab,
                const int* __restrict__ col, const int* __restrict__ srcv,
                const float* __restrict__ ea,
                const int* __restrict__ rowptr, const int* __restrict__ deg,
                const float* __restrict__ W_edge, const float* __restrict__ b_edge,
                const float* __restrict__ eps, int layer,
                __hip_bfloat16* __restrict__ u, int n) {
    int lane = threadIdx.x & 63;
    int v = __builtin_amdgcn_readfirstlane(blockIdx.x * 4 + (threadIdx.x >> 6));
    if (v >= n) return;   // wave-uniform

    float we[7];
#pragma unroll
    for (int k = 0; k < 7; ++k) we[k] = W_edge[k * DD + lane];
    float be = b_edge[lane];
    float epsv = 1.f + eps[layer];

    float acc = 0.f;
    int beg = rowptr[v];
    int dv  = deg[v];
    int end = beg + dv;          // true end; slots padded up to padq(dv)
    for (int p = beg; p < end; p += PB) {
        int mm = end - p;        // wave-uniform
        // --- unconditional index loads (pad slots exist and are safe)
        int S[PB];
#pragma unroll
        for (int j = 0; j < PB; ++j) S[j] = srcv[p + j];
        // --- unconditional gathers
        __hip_bfloat16 hv[PB];
#pragma unroll
        for (int j = 0; j < PB; ++j) hv[j] = hb_in[(size_t)S[j] * DD + lane];
        // --- unconditional edge-record loads (wave-uniform -> scalarized)
        float ev[PB][7];
        if (PACKED) {
            short8 eb[PB];
#pragma unroll
            for (int j = 0; j < PB; ++j)
                eb[j] = *((const short8*)(eab + (size_t)(p + j) * 8));
#pragma unroll
            for (int j = 0; j < PB; ++j)
#pragma unroll
                for (int k = 0; k < 7; ++k) ev[j][k] = bf2f(eb[j][k]);
        } else {
            int EJ[PB];
#pragma unroll
            for (int j = 0; j < PB; ++j) EJ[j] = col[p + j];
#pragma unroll
            for (int j = 0; j < PB; ++j) {
                const float* a = ea + (size_t)EJ[j] * 7;
#pragma unroll
                for (int k = 0; k < 7; ++k) ev[j][k] = a[k];
            }
        }
        // --- guarded VALU (uniform branches, pads skipped)
#pragma unroll
        for (int j = 0; j < PB; ++j) {
            if (j < mm) {
                float emb = be + ev[j][0] * we[0] + ev[j][1] * we[1] + ev[j][2] * we[2]
                               + ev[j][3] * we[3] + ev[j][4] * we[4] + ev[j][5] * we[5]
                               + ev[j][6] * we[6];
                float tv = __bfloat162float(hv[j]) + emb;
                acc += (tv > 0.f) ? tv : 0.f;
            }
        }
    }
    float self = __bfloat162float(hb_in[(size_t)v * DD + lane]);
    u[(size_t)v * DD + lane] = __float2bfloat16(epsv * self + acc);
}

// ---------------------------------------------------------------------------
// MFMA MLP: h_out = relu(u @ W + b). Wave handles 16 nodes; A from global u,
// B from pre-transposed bf16 Wt[c][k]. Fragment mapping validated in R5.
__global__ __launch_bounds__(256, 4)
void mlp_mfma_kernel(const __hip_bfloat16* __restrict__ u,
                     const __hip_bfloat16* __restrict__ Wt,
                     const float* __restrict__ bmlp,
                     __hip_bfloat16* __restrict__ hb_out, int n) {
    int lane = threadIdx.x & 63;
    int wid  = threadIdx.x >> 6;
    int colx = lane & 15;
    int quad = lane >> 4;
    int v0 = __builtin_amdgcn_readfirstlane((blockIdx.x * 4 + wid) * 16);
    if (v0 >= n) return;

    short8 wf[4][2];
#pragma unroll
    for (int t = 0; t < 4; ++t)
#pragma unroll
        for (int s = 0; s < 2; ++s)
            wf[t][s] = *((const short8*)(Wt + (size_t)(t * 16 + colx) * DD + s * 32 + quad * 8));
    float bias[4];
#pragma unroll
    for (int t = 0; t < 4; ++t) bias[t] = bmlp[t * 16 + colx];

    int vr = v0 + colx;
    int vrc = (vr < n) ? vr : (n - 1);
    const __hip_bfloat16* up = u + (size_t)vrc * DD;
    short8 a0 = *((const short8*)(up + quad * 8));
    short8 a1 = *((const short8*)(up + 32 + quad * 8));

    f32x4 acc[4] = {{0.f, 0.f, 0.f, 0.f}, {0.f, 0.f, 0.f, 0.f},
                    {0.f, 0.f, 0.f, 0.f}, {0.f, 0.f, 0.f, 0.f}};
#pragma unroll
    for (int t = 0; t < 4; ++t) {
        acc[t] = __builtin_amdgcn_mfma_f32_16x16x32_bf16(a0, wf[t][0], acc[t], 0, 0, 0);
        acc[t] = __builtin_amdgcn_mfma_f32_16x16x32_bf16(a1, wf[t][1], acc[t], 0, 0, 0);
    }

#pragma unroll
    for (int r = 0; r < 4; ++r) {
        int v = v0 + quad * 4 + r;
        if (v < n) {
#pragma unroll
            for (int t = 0; t < 4; ++t) {
                float val = acc[t][r] + bias[t];
                val = (val > 0.f) ? val : 0.f;
                hb_out[(size_t)v * DD + t * 16 + colx] = __float2bfloat16(val);
            }
        }
    }
}

// ---------------------------------------------------------------------------
// Pool partials: one block per (graph, layer). Zero atomics.
__global__ void pool_part_kernel(const __hip_bfloat16* __restrict__ htabs, size_t lstride,
                                 const int* __restrict__ batch,
                                 float* __restrict__ g_sum, int n, int G) {
    __shared__ float part[4][DD];
    __shared__ int bnd[2];
    int g = blockIdx.x / NL;
    int q = blockIdx.x % NL;
    int tid = threadIdx.x;
    if (tid < 2) {
        int target = g + tid;
        int lo = 0, hi = n;
        while (lo < hi) { int mid = (lo + hi) >> 1; if (batch[mid] < target) lo = mid + 1; else hi = mid; }
        bnd[tid] = lo;
    }
    __syncthreads();
    int lb = bnd[0], ub = bnd[1];
    int w = tid >> 6, f = tid & 63;
    const __hip_bfloat16* T = htabs + (size_t)q * lstride;
    float s = 0.f;
    for (int v = lb + w; v < ub; v += 4)
        s += __bfloat162float(T[(size_t)v * DD + f]);
    part[w][f] = s;
    __syncthreads();
    if (tid < DD) {
        float tot = part[0][f] + part[1][f] + part[2][f] + part[3][f];
        float c = (float)(ub - lb);
        if (c < 1.f) c = 1.f;
        g_sum[(size_t)g * LD + q * DD + f] = tot / c;
    }
}

__global__ void readout_mean_kernel(const float* __restrict__ g_mean,
                                    const float* __restrict__ W_pred,
                                    const float* __restrict__ b_pred,
                                    float* __restrict__ out, int G) {
    int id = blockIdx.x * blockDim.x + threadIdx.x;
    if (id >= G * NT) return;
    int g = id / NT, t = id % NT;
    float acc = b_pred[t];
    const float* gs = g_mean + (size_t)g * LD;
    for (int k = 0; k < LD; ++k) acc += gs[k] * W_pred[k * NT + t];
    out[id] = acc;
}

// ---------------------------------------------------------------------------
// Tier-2 fallback pool (run accumulation) + readout
__global__ void pool_kernel(const __hip_bfloat16* __restrict__ h, const int* __restrict__ batch,
                            float* __restrict__ g_sum, int layer, int n) {
    int wave = (blockIdx.x * blockDim.x + threadIdx.x) >> 6;
    int l = threadIdx.x & 63;
    int v0 = wave * 64;
    if (v0 >= n) return;
    int vend = min(v0 + 64, n);
    int cur = batch[v0];
    float acc = 0.f;
    for (int v = v0; v < vend; ++v) {
        int bv = batch[v];
        if (bv != cur) {
            atomicAdd(&g_sum[(size_t)cur * LD + layer * DD + l], acc);
            acc = 0.f;
            cur = bv;
        }
        acc += __bfloat162float(h[(size_t)v * DD + l]);
    }
    atomicAdd(&g_sum[(size_t)cur * LD + layer * DD + l], acc);
}

__global__ void graph_cnt_kernel(const int* __restrict__ batch, int* __restrict__ cnt,
                                 int n, int G) {
    int g = blockIdx.x * blockDim.x + threadIdx.x;
    if (g >= G) return;
    int lo = 0, hi = n;
    while (lo < hi) { int mid = (lo + hi) >> 1; if (batch[mid] < g) lo = mid + 1; else hi = mid; }
    int lb0 = lo;
    lo = lb0; hi = n;
    while (lo < hi) { int mid = (lo + hi) >> 1; if (batch[mid] < g + 1) lo = mid + 1; else hi = mid; }
    cnt[g] = lo - lb0;
}

__global__ void readout_kernel(const float* __restrict__ g_sum, const int* __restrict__ cnt,
                               const float* __restrict__ W_pred, const float* __restrict__ b_pred,
                               float* __restrict__ out, int G) {
    int id = blockIdx.x * blockDim.x + threadIdx.x;
    if (id >= G * NT) return;
    int g = id / NT, t = id % NT;
    float c = (float)cnt[g];
    if (c < 1.f) c = 1.f;
    float inv = 1.f / c;
    float acc = b_pred[t];
    const float* gs = g_sum + (size_t)g * LD;
    for (int k = 0; k < LD; ++k) acc += gs[k] * inv * W_pred[k * NT + t];
    out[id] = acc;
}

// ---------------------------------------------------------------------------
extern "C" void kernel_launch(void* const* d_in, const int* in_sizes, int n_in,
                              void* d_out, int out_size, void* d_ws, size_t ws_size,
                              hipStream_t stream) {
    const float* x       = (const float*)d_in[0];
    const int*   eidx    = (const int*)d_in[1];
    const float* ea      = (const float*)d_in[2];
    const int*   batch   = (const int*)d_in[3];
    const float* W_edge  = (const float*)d_in[4];
    const float* b_edge  = (const float*)d_in[5];
    const float* eps     = (const float*)d_in[6];
    const float* W_mlp   = (const float*)d_in[7];
    const float* b_mlp   = (const float*)d_in[8];
    const float* W_pred  = (const float*)d_in[9];
    const float* b_pred  = (const float*)d_in[10];
    float* out = (float*)d_out;

    const int N = in_sizes[3];          // 100000
    const int E = in_sizes[2] / 7;      // 1250000
    const int G = out_size / NT;        // 128
    const int* src = eidx;              // edge_index[0]
    const int* dst = eidx + E;          // edge_index[1]
    const int NC = (N + 1023) / 1024;
    const size_t SLOTS = (size_t)E + (size_t)(PB - 1) * N;   // padded-slot capacity

    const size_t S_h = (size_t)N * DD * 2;   // one bf16 table
    const size_t small = (size_t)N * 4 + (size_t)(N + 4) * 4 + (size_t)N * 4 + 4096
                       + (size_t)NL * DD * DD * 2              // Wt
                       + (size_t)G * LD * 4 + (((size_t)G * 4 + 15) & ~(size_t)15);
    const size_t needA = 7 * S_h + small + SLOTS * 20;  // bf16 records + srcv
    const size_t needB = 7 * S_h + small + SLOTS * 8;   // col + srcv
    const int tier = (ws_size >= needA) ? 0 : (ws_size >= needB) ? 1 : 2;
    const int nTab = (tier <= 1) ? 6 : 2;

    char* w = (char*)d_ws;
    __hip_bfloat16* hbt = (__hip_bfloat16*)w;  w += (size_t)nTab * S_h;
    __hip_bfloat16* u   = (__hip_bfloat16*)w;  w += S_h;
    __hip_bfloat16* Wt  = (__hip_bfloat16*)w;  w += (size_t)NL * DD * DD * 2;
    int*   deg    = (int*)w;                   w += (size_t)N * 4;
    int*   rowptr = (int*)w;                   w += (size_t)(N + 4) * 4;
    int*   cursor = (int*)w;                   w += (size_t)N * 4;
    int*   csum   = (int*)w;                   w += 4096;
    float* g_sum  = (float*)w;                 w += (size_t)G * LD * 4;
    int*   cnt    = (int*)w;                   w += ((size_t)G * 4 + 15) & ~(size_t)15;
    short* eab = nullptr; int* col = nullptr; int* srcv = nullptr;
    if (tier == 0) {
        eab  = (short*)w;  w += SLOTS * 16;    // 16-B aligned
        srcv = (int*)w;
    } else {
        col  = (int*)w;    w += SLOTS * 4;
        srcv = (int*)w;
    }
    const bool packed = (tier == 0);

    hipMemsetAsync(deg, 0, (size_t)N * 4, stream);
    if (tier == 2) hipMemsetAsync(g_sum, 0, (size_t)G * LD * 4, stream);

    // Fused init: bf16 convert + W transpose + degree histogram
    {
        size_t n1 = (size_t)N * DD;
        size_t tot = n1 + (size_t)(NL * DD * DD) + (size_t)E;
        init_kernel<<<(unsigned)((tot + 255) / 256), 256, 0, stream>>>(
            x, hbt, n1, W_mlp, Wt, NL * DD * DD, dst, deg, E);
    }

    // CSR build (padded rows): scan -> single-pass scatter fill -> pad
    chunksum_kernel<<<NC, 256, 0, stream>>>(deg, csum, N);
    scansums_kernel<<<1, 256, 0, stream>>>(csum, NC, rowptr + N);
    chunkscan_kernel<<<NC, 256, 0, stream>>>(deg, csum, rowptr, cursor, N);
    if (packed)
        fill_kernel<true><<<(E + 255) / 256, 256, 0, stream>>>(dst, src, ea, cursor,
                                                               eab, col, srcv, E);
    else
        fill_kernel<false><<<(E + 255) / 256, 256, 0, stream>>>(dst, src, ea, cursor,
                                                                eab, col, srcv, E);
    padfill_kernel<<<(N + 255) / 256, 256, 0, stream>>>(deg, rowptr, srcv,
                                                        col ? col : srcv,
                                                        col ? 1 : 0, N);

    int aggBlocks = (N + 3) / 4;
    int mlpBlocks = (N + 63) / 64;
    for (int i = 0; i < NL; ++i) {
        __hip_bfloat16* hin  = (tier <= 1) ? (hbt + (size_t)i * N * DD)
                                           : (hbt + (size_t)(i & 1) * N * DD);
        __hip_bfloat16* hout = (tier <= 1) ? (hbt + (size_t)(i + 1) * N * DD)
                                           : (hbt + (size_t)((i + 1) & 1) * N * DD);
        if (packed)
            agg_kernel<true><<<aggBlocks, 256, 0, stream>>>(
                hin, eab, col, srcv, ea, rowptr, deg, W_edge, b_edge, eps, i, u, N);
        else
            agg_kernel<false><<<aggBlocks, 256, 0, stream>>>(
                hin, eab, col, srcv, ea, rowptr, deg, W_edge, b_edge, eps, i, u, N);
        mlp_mfma_kernel<<<mlpBlocks, 256, 0, stream>>>(
            u, Wt + (size_t)i * DD * DD, b_mlp + (size_t)i * DD, hout, N);
        if (tier == 2)
            pool_kernel<<<((N + 63) / 64 * 64 + 255) / 256, 256, 0, stream>>>(hout, batch,
                                                                              g_sum, i, N);
    }

    if (tier <= 1) {
        pool_part_kernel<<<G * NL, 256, 0, stream>>>(hbt + (size_t)N * DD, (size_t)N * DD,
                                                     batch, g_sum, N, G);
        readout_mean_kernel<<<(G * NT + 255) / 256, 256, 0, stream>>>(g_sum, W_pred, b_pred,
                                                                      out, G);
    } else {
        graph_cnt_kernel<<<1, 128, 0, stream>>>(batch, cnt, N, G);
        readout_kernel<<<(G * NT + 255) / 256, 256, 0, stream>>>(g_sum, cnt, W_pred, b_pred,
                                                                 out, G);
    }
}